// Round 1
// baseline (777.454 us; speedup 1.0000x reference)
//
#include <hip/hip_runtime.h>
#include <hip/hip_bf16.h>
#include <stdint.h>
#include <math.h>

// SparseMoeBlock: 8 experts, top-2, H=2048, I=1408, T=8192, fp32 in/out.
// Sparse formulation: router -> top2 -> compacted per-expert slot lists ->
// bf16 MFMA GEMM1 (fused silu*up) -> bf16 MFMA GEMM2 (weighted atomic add).

#define E_ 8
#define H_ 2048
#define I_ 1408
#define T_ 8192
#define NSLOT (T_ * 2)

typedef __bf16 bf16;
typedef bf16 bf16x8 __attribute__((ext_vector_type(8)));
typedef float f32x4 __attribute__((ext_vector_type(4)));

__device__ inline void gl2lds16(const void* g, void* l) {
  __builtin_amdgcn_global_load_lds(
      (const __attribute__((address_space(1))) unsigned int*)g,
      (__attribute__((address_space(3))) unsigned int*)l, 16, 0, 0);
}

// ---------------- fp32 -> bf16 conversion (8 elems / thread) ----------------
__global__ __launch_bounds__(256) void cvt_k(const float* __restrict__ in,
                                             bf16* __restrict__ out, int n8) {
  int stride = gridDim.x * blockDim.x;
  for (int i = blockIdx.x * blockDim.x + threadIdx.x; i < n8; i += stride) {
    const float4* p = (const float4*)in + (size_t)i * 2;
    float4 a = p[0], b = p[1];
    bf16x8 o;
    o[0] = (bf16)a.x; o[1] = (bf16)a.y; o[2] = (bf16)a.z; o[3] = (bf16)a.w;
    o[4] = (bf16)b.x; o[5] = (bf16)b.y; o[6] = (bf16)b.z; o[7] = (bf16)b.w;
    *((bf16x8*)out + i) = o;
  }
}

// ---------------- router: logits, top-2, normalized weights ----------------
__global__ __launch_bounds__(256) void router_k(const float* __restrict__ X,
                                                const float* __restrict__ R,
                                                int* __restrict__ sel,
                                                float* __restrict__ wts) {
  int lane = threadIdx.x & 63;
  int t = blockIdx.x * 4 + (threadIdx.x >> 6);
  const float4* x4 = (const float4*)(X + (size_t)t * H_);
  float acc[E_];
#pragma unroll
  for (int e = 0; e < E_; ++e) acc[e] = 0.f;
#pragma unroll
  for (int i = 0; i < H_ / 256; ++i) {  // 8 iters of float4
    float4 x = x4[i * 64 + lane];
#pragma unroll
    for (int e = 0; e < E_; ++e) {
      float4 r = ((const float4*)(R + (size_t)e * H_))[i * 64 + lane];
      acc[e] += x.x * r.x + x.y * r.y + x.z * r.z + x.w * r.w;
    }
  }
#pragma unroll
  for (int e = 0; e < E_; ++e)
#pragma unroll
    for (int off = 32; off > 0; off >>= 1) acc[e] += __shfl_xor(acc[e], off);
  if (lane == 0) {
    int e1 = 0; float l1 = acc[0];
#pragma unroll
    for (int e = 1; e < E_; ++e) if (acc[e] > l1) { l1 = acc[e]; e1 = e; }
    int e2 = -1; float l2 = -3.4e38f;
#pragma unroll
    for (int e = 0; e < E_; ++e) if (e != e1 && acc[e] > l2) { l2 = acc[e]; e2 = e; }
    // softmax + top-2 renorm collapses: w1 = 1/(1+exp(l2-l1)), w2 = 1-ish
    float d = expf(l2 - l1);
    float inv = 1.f / (1.f + d);
    sel[2 * t] = e1; sel[2 * t + 1] = e2;
    wts[2 * t] = inv; wts[2 * t + 1] = d * inv;
  }
}

// ---------------- routing bookkeeping ----------------
// ctl[0..7]=counts, ctl[8..15]=offsets, ctl[16..23]=cursors
__global__ void count_k(const int* __restrict__ sel, int* __restrict__ ctl) {
  int i = blockIdx.x * blockDim.x + threadIdx.x;
  if (i < NSLOT) atomicAdd(&ctl[sel[i]], 1);
}
__global__ void prefix_k(int* __restrict__ ctl) {
  if (threadIdx.x == 0) {
    int off = 0;
    for (int e = 0; e < E_; ++e) { ctl[8 + e] = off; ctl[16 + e] = off; off += ctl[e]; }
  }
}
__global__ void scatter_k(const int* __restrict__ sel, const float* __restrict__ wts,
                          int* __restrict__ ctl, int* __restrict__ tok,
                          float* __restrict__ sw) {
  int i = blockIdx.x * blockDim.x + threadIdx.x;
  if (i < NSLOT) {
    int e = sel[i];
    int pos = atomicAdd(&ctl[16 + e], 1);
    tok[pos] = i >> 1;
    sw[pos] = wts[i];
  }
}

// ---------------- GEMM1: act = silu(Xg @ Wg^T) * (Xg @ Wu^T) ----------------
// tile: 128 rows x 64 act-cols (gate tile + up tile), BK=64, 4 waves (2x2)
__global__ __launch_bounds__(256) void gemm1_k(const bf16* __restrict__ Xb,
                                               const bf16* __restrict__ Wgu,
                                               const int* __restrict__ ctl,
                                               const int* __restrict__ tok,
                                               bf16* __restrict__ act) {
  const int e = blockIdx.z;
  const int cnt = ctl[e];
  const int m0 = blockIdx.y * 128;
  if (m0 >= cnt) return;
  const int base = ctl[8 + e];
  const int j0 = blockIdx.x * 64;

  __shared__ bf16 lA[128 * 64];
  __shared__ bf16 lBg[64 * 64];
  __shared__ bf16 lBu[64 * 64];

  const int t = threadIdx.x;
  const int lane = t & 63;
  const int wr = (t >> 7) & 1;
  const int wc = (t >> 6) & 1;
  const bf16* wg = Wgu + (size_t)e * (2 * I_) * H_;

  // staging descriptors; XOR swizzle (chunk ^= row&7) applied on the GLOBAL
  // source address so LDS dest stays linear (global_load_lds requirement)
  const bf16* asrc[4]; int aoff[4];
#pragma unroll
  for (int c = 0; c < 4; ++c) {
    int L = c * 256 + t;
    int row = L >> 3, cc = (L & 7) ^ (row & 7);
    int r = m0 + row; if (r >= cnt) r = cnt - 1;
    asrc[c] = Xb + (size_t)tok[base + r] * H_ + cc * 8;
    aoff[c] = L * 16;
  }
  const bf16* gsrc[2]; const bf16* usrc[2]; int boff[2];
#pragma unroll
  for (int c = 0; c < 2; ++c) {
    int L = c * 256 + t;
    int row = L >> 3, cc = (L & 7) ^ (row & 7);
    gsrc[c] = wg + (size_t)(j0 + row) * H_ + cc * 8;
    usrc[c] = wg + (size_t)(I_ + j0 + row) * H_ + cc * 8;
    boff[c] = L * 16;
  }

  f32x4 zero = {0.f, 0.f, 0.f, 0.f};
  f32x4 ag[4][2], au[4][2];
#pragma unroll
  for (int m = 0; m < 4; ++m)
#pragma unroll
    for (int n = 0; n < 2; ++n) { ag[m][n] = zero; au[m][n] = zero; }

  const int lo = lane & 15, hi = lane >> 4;

  for (int k0 = 0; k0 < H_; k0 += 64) {
#pragma unroll
    for (int c = 0; c < 4; ++c) gl2lds16(asrc[c] + k0, (char*)lA + aoff[c]);
#pragma unroll
    for (int c = 0; c < 2; ++c) {
      gl2lds16(gsrc[c] + k0, (char*)lBg + boff[c]);
      gl2lds16(usrc[c] + k0, (char*)lBu + boff[c]);
    }
    asm volatile("s_waitcnt vmcnt(0)" ::: "memory");
    __syncthreads();
#pragma unroll
    for (int kk = 0; kk < 2; ++kk) {
      const int chunk = kk * 4 + hi;
      bf16x8 af[4], bg[2], bu[2];
#pragma unroll
      for (int m = 0; m < 4; ++m) {
        int row = wr * 64 + m * 16 + lo;
        af[m] = *(const bf16x8*)((const char*)lA + row * 128 + ((chunk ^ (row & 7)) * 16));
      }
#pragma unroll
      for (int n = 0; n < 2; ++n) {
        int row = wc * 32 + n * 16 + lo;
        int sw = (chunk ^ (row & 7)) * 16;
        bg[n] = *(const bf16x8*)((const char*)lBg + row * 128 + sw);
        bu[n] = *(const bf16x8*)((const char*)lBu + row * 128 + sw);
      }
#pragma unroll
      for (int m = 0; m < 4; ++m)
#pragma unroll
        for (int n = 0; n < 2; ++n) {
          ag[m][n] = __builtin_amdgcn_mfma_f32_16x16x32_bf16(af[m], bg[n], ag[m][n], 0, 0, 0);
          au[m][n] = __builtin_amdgcn_mfma_f32_16x16x32_bf16(af[m], bu[n], au[m][n], 0, 0, 0);
        }
    }
    __syncthreads();
  }

#pragma unroll
  for (int m = 0; m < 4; ++m)
#pragma unroll
    for (int r = 0; r < 4; ++r) {
      int row = m0 + wr * 64 + m * 16 + hi * 4 + r;
      if (row < cnt) {
        bf16* dst = act + (size_t)(base + row) * I_ + j0 + wc * 32 + lo;
#pragma unroll
        for (int n = 0; n < 2; ++n) {
          float g = ag[m][n][r], u = au[m][n][r];
          dst[n * 16] = (bf16)(g / (1.f + expf(-g)) * u);
        }
      }
    }
}

// ---------------- GEMM2: out[tok] += w * (act @ Wd^T) ----------------
// tile: 128 rows x 128 cols, BK=64, 4 waves (2x2), fp32 atomic scatter-add
__global__ __launch_bounds__(256) void gemm2_k(const bf16* __restrict__ act,
                                               const bf16* __restrict__ Wd,
                                               const int* __restrict__ ctl,
                                               const int* __restrict__ tok,
                                               const float* __restrict__ sw,
                                               float* __restrict__ out) {
  const int e = blockIdx.z;
  const int cnt = ctl[e];
  const int m0 = blockIdx.y * 128;
  if (m0 >= cnt) return;
  const int base = ctl[8 + e];
  const int n0 = blockIdx.x * 128;

  __shared__ bf16 lA[128 * 64];
  __shared__ bf16 lB[128 * 64];

  const int t = threadIdx.x;
  const int lane = t & 63;
  const int wr = (t >> 7) & 1;
  const int wc = (t >> 6) & 1;
  const bf16* wd = Wd + (size_t)e * H_ * I_;

  const bf16* asrc[4]; int aoff[4];
#pragma unroll
  for (int c = 0; c < 4; ++c) {
    int L = c * 256 + t;
    int row = L >> 3, cc = (L & 7) ^ (row & 7);
    int r = m0 + row; if (r >= cnt) r = cnt - 1;
    asrc[c] = act + (size_t)(base + r) * I_ + cc * 8;
    aoff[c] = L * 16;
  }
  const bf16* bsrc[4]; int boff[4];
#pragma unroll
  for (int c = 0; c < 4; ++c) {
    int L = c * 256 + t;
    int row = L >> 3, cc = (L & 7) ^ (row & 7);
    bsrc[c] = wd + (size_t)(n0 + row) * I_ + cc * 8;
    boff[c] = L * 16;
  }

  f32x4 zero = {0.f, 0.f, 0.f, 0.f};
  f32x4 acc[4][4];
#pragma unroll
  for (int m = 0; m < 4; ++m)
#pragma unroll
    for (int n = 0; n < 4; ++n) acc[m][n] = zero;

  const int lo = lane & 15, hi = lane >> 4;

  for (int k0 = 0; k0 < I_; k0 += 64) {
#pragma unroll
    for (int c = 0; c < 4; ++c) gl2lds16(asrc[c] + k0, (char*)lA + aoff[c]);
#pragma unroll
    for (int c = 0; c < 4; ++c) gl2lds16(bsrc[c] + k0, (char*)lB + boff[c]);
    asm volatile("s_waitcnt vmcnt(0)" ::: "memory");
    __syncthreads();
#pragma unroll
    for (int kk = 0; kk < 2; ++kk) {
      const int chunk = kk * 4 + hi;
      bf16x8 af[4], bb[4];
#pragma unroll
      for (int m = 0; m < 4; ++m) {
        int row = wr * 64 + m * 16 + lo;
        af[m] = *(const bf16x8*)((const char*)lA + row * 128 + ((chunk ^ (row & 7)) * 16));
      }
#pragma unroll
      for (int n = 0; n < 4; ++n) {
        int row = wc * 64 + n * 16 + lo;
        bb[n] = *(const bf16x8*)((const char*)lB + row * 128 + ((chunk ^ (row & 7)) * 16));
      }
#pragma unroll
      for (int m = 0; m < 4; ++m)
#pragma unroll
        for (int n = 0; n < 4; ++n)
          acc[m][n] = __builtin_amdgcn_mfma_f32_16x16x32_bf16(af[m], bb[n], acc[m][n], 0, 0, 0);
    }
    __syncthreads();
  }

#pragma unroll
  for (int m = 0; m < 4; ++m)
#pragma unroll
    for (int r = 0; r < 4; ++r) {
      int row = m0 + wr * 64 + m * 16 + hi * 4 + r;
      if (row < cnt) {
        int token = tok[base + row];
        float w = sw[base + row];
        float* dst = out + (size_t)token * H_ + n0 + wc * 64 + lo;
#pragma unroll
        for (int n = 0; n < 4; ++n) atomicAdd(&dst[n * 16], w * acc[m][n][r]);
      }
    }
}

// ---------------- host launch ----------------
extern "C" void kernel_launch(void* const* d_in, const int* in_sizes, int n_in,
                              void* d_out, int out_size, void* d_ws, size_t ws_size,
                              hipStream_t stream) {
  const float* X = (const float*)d_in[0];
  const float* R = (const float*)d_in[1];
  const float* Wgu = (const float*)d_in[2];
  const float* Wd = (const float*)d_in[3];
  float* out = (float*)d_out;

  char* ws = (char*)d_ws;
  size_t o = 0;
  auto alloc = [&](size_t sz) { void* p = ws + o; o += (sz + 255) & ~(size_t)255; return p; };
  bf16* wgu_bf = (bf16*)alloc(sizeof(bf16) * (size_t)E_ * 2 * I_ * H_);
  bf16* wd_bf  = (bf16*)alloc(sizeof(bf16) * (size_t)E_ * H_ * I_);
  bf16* xbf    = (bf16*)alloc(sizeof(bf16) * (size_t)T_ * H_);
  bf16* actb   = (bf16*)alloc(sizeof(bf16) * (size_t)NSLOT * I_);
  int* sel     = (int*)alloc(4 * NSLOT);
  float* wts   = (float*)alloc(4 * NSLOT);
  int* tokb    = (int*)alloc(4 * NSLOT);
  float* swb   = (float*)alloc(4 * NSLOT);
  int* ctl     = (int*)alloc(4 * 32);

  hipMemsetAsync(d_out, 0, sizeof(float) * (size_t)out_size, stream);
  hipMemsetAsync(ctl, 0, 4 * 32, stream);

  cvt_k<<<2048, 256, 0, stream>>>(Wgu, wgu_bf, (int)((size_t)E_ * 2 * I_ * H_ / 8));
  cvt_k<<<2048, 256, 0, stream>>>(Wd, wd_bf, (int)((size_t)E_ * H_ * I_ / 8));
  cvt_k<<<2048, 256, 0, stream>>>(X, xbf, (int)((size_t)T_ * H_ / 8));
  router_k<<<T_ / 4, 256, 0, stream>>>(X, R, sel, wts);
  count_k<<<NSLOT / 256, 256, 0, stream>>>(sel, ctl);
  prefix_k<<<1, 64, 0, stream>>>(ctl);
  scatter_k<<<NSLOT / 256, 256, 0, stream>>>(sel, wts, ctl, tokb, swb);
  gemm1_k<<<dim3(I_ / 64, T_ / 128, E_), 256, 0, stream>>>(xbf, wgu_bf, ctl, tokb, actb);
  gemm2_k<<<dim3(H_ / 128, T_ / 128, E_), 256, 0, stream>>>(actb, wd_bf, ctl, tokb, swb, out);
}

// Round 2
// 654.245 us; speedup vs baseline: 1.1883x; 1.1883x over previous
//
#include <hip/hip_runtime.h>
#include <hip/hip_bf16.h>
#include <stdint.h>
#include <math.h>

// SparseMoeBlock: 8 experts, top-2, H=2048, I=1408, T=8192, fp32 in/out.
// Router -> top2 -> compacted per-expert slot lists ->
// bf16 MFMA GEMM1 (fused silu*up) -> bf16 MFMA GEMM2 (weighted atomic add).
// R2: 1-D grids + chunked XCD swizzle (expert-per-XCD L2 locality),
//     2-phase double-buffered K-loops (stage next || compute cur),
//     X-cvt folded into router, __expf in silu.

#define E_ 8
#define H_ 2048
#define I_ 1408
#define T_ 8192
#define NSLOT (T_ * 2)

typedef __bf16 bf16;
typedef bf16 bf16x4 __attribute__((ext_vector_type(4)));
typedef bf16 bf16x8 __attribute__((ext_vector_type(8)));
typedef float f32x4 __attribute__((ext_vector_type(4)));

__device__ inline void gl2lds16(const void* g, void* l) {
  __builtin_amdgcn_global_load_lds(
      (const __attribute__((address_space(1))) unsigned int*)g,
      (__attribute__((address_space(3))) unsigned int*)l, 16, 0, 0);
}

// ---------------- fp32 -> bf16 conversion (weights) ----------------
__global__ __launch_bounds__(256) void cvt_k(const float* __restrict__ in,
                                             bf16* __restrict__ out, int n8) {
  int stride = gridDim.x * blockDim.x;
  for (int i = blockIdx.x * blockDim.x + threadIdx.x; i < n8; i += stride) {
    const float4* p = (const float4*)in + (size_t)i * 2;
    float4 a = p[0], b = p[1];
    bf16x8 o;
    o[0] = (bf16)a.x; o[1] = (bf16)a.y; o[2] = (bf16)a.z; o[3] = (bf16)a.w;
    o[4] = (bf16)b.x; o[5] = (bf16)b.y; o[6] = (bf16)b.z; o[7] = (bf16)b.w;
    *((bf16x8*)out + i) = o;
  }
}

// ------------- router: logits, top-2 weights; also X -> bf16 -------------
__global__ __launch_bounds__(256) void router_k(const float* __restrict__ X,
                                                const float* __restrict__ R,
                                                bf16* __restrict__ xbf,
                                                int* __restrict__ sel,
                                                float* __restrict__ wts) {
  int lane = threadIdx.x & 63;
  int t = blockIdx.x * 4 + (threadIdx.x >> 6);
  const float4* x4 = (const float4*)(X + (size_t)t * H_);
  bf16x4* xb4 = (bf16x4*)(xbf + (size_t)t * H_);
  float acc[E_];
#pragma unroll
  for (int e = 0; e < E_; ++e) acc[e] = 0.f;
#pragma unroll
  for (int i = 0; i < H_ / 256; ++i) {  // 8 iters of float4
    float4 x = x4[i * 64 + lane];
    bf16x4 xo; xo[0] = (bf16)x.x; xo[1] = (bf16)x.y; xo[2] = (bf16)x.z; xo[3] = (bf16)x.w;
    xb4[i * 64 + lane] = xo;
#pragma unroll
    for (int e = 0; e < E_; ++e) {
      float4 r = ((const float4*)(R + (size_t)e * H_))[i * 64 + lane];
      acc[e] += x.x * r.x + x.y * r.y + x.z * r.z + x.w * r.w;
    }
  }
#pragma unroll
  for (int e = 0; e < E_; ++e)
#pragma unroll
    for (int off = 32; off > 0; off >>= 1) acc[e] += __shfl_xor(acc[e], off);
  if (lane == 0) {
    int e1 = 0; float l1 = acc[0];
#pragma unroll
    for (int e = 1; e < E_; ++e) if (acc[e] > l1) { l1 = acc[e]; e1 = e; }
    int e2 = -1; float l2 = -3.4e38f;
#pragma unroll
    for (int e = 0; e < E_; ++e) if (e != e1 && acc[e] > l2) { l2 = acc[e]; e2 = e; }
    float d = expf(l2 - l1);
    float inv = 1.f / (1.f + d);
    sel[2 * t] = e1; sel[2 * t + 1] = e2;
    wts[2 * t] = inv; wts[2 * t + 1] = d * inv;
  }
}

// ---------------- routing bookkeeping ----------------
// ctl[0..7]=counts, ctl[8..15]=offsets, ctl[16..23]=cursors
__global__ void count_k(const int* __restrict__ sel, int* __restrict__ ctl) {
  int i = blockIdx.x * blockDim.x + threadIdx.x;
  if (i < NSLOT) atomicAdd(&ctl[sel[i]], 1);
}
__global__ void prefix_k(int* __restrict__ ctl) {
  if (threadIdx.x == 0) {
    int off = 0;
    for (int e = 0; e < E_; ++e) { ctl[8 + e] = off; ctl[16 + e] = off; off += ctl[e]; }
  }
}
__global__ void scatter_k(const int* __restrict__ sel, const float* __restrict__ wts,
                          int* __restrict__ ctl, int* __restrict__ tok,
                          float* __restrict__ sw) {
  int i = blockIdx.x * blockDim.x + threadIdx.x;
  if (i < NSLOT) {
    int e = sel[i];
    int pos = atomicAdd(&ctl[16 + e], 1);
    tok[pos] = i >> 1;
    sw[pos] = wts[i];
  }
}

// ---------------- GEMM1: act = silu(Xg @ Wg^T) * (Xg @ Wu^T) ----------------
// tile: 128 rows x 64 act-cols (gate+up), BK=64, 4 waves (2x2), 2-ph dbuf
__global__ __launch_bounds__(256) void gemm1_k(const bf16* __restrict__ Xb,
                                               const bf16* __restrict__ Wgu,
                                               const int* __restrict__ ctl,
                                               const int* __restrict__ tok,
                                               bf16* __restrict__ act) {
  constexpr int NJ = I_ / 64;        // 22
  constexpr int NM = T_ / 128;       // 64
  constexpr int NB = NJ * NM * E_;   // 11264 (divisible by 8)
  // chunked bijective XCD swizzle: physical bid%8 = XCD; give each XCD a
  // contiguous logical range -> one expert per XCD (NJ*NM = 1408 = NB/8)
  const int L0 = ((int)blockIdx.x & 7) * (NB >> 3) + ((int)blockIdx.x >> 3);
  const int e = L0 / (NJ * NM);
  const int rem = L0 - e * (NJ * NM);
  const int m0 = (rem / NJ) * 128;   // j innermost -> A-tile reused in L2
  const int j0 = (rem % NJ) * 64;
  const int cnt = ctl[e];
  if (m0 >= cnt) return;
  const int base = ctl[8 + e];

  __shared__ bf16 lA[2][128 * 64];
  __shared__ bf16 lBg[2][64 * 64];
  __shared__ bf16 lBu[2][64 * 64];

  const int t = threadIdx.x;
  const int lane = t & 63;
  const int wr = (t >> 7) & 1;
  const int wc = (t >> 6) & 1;
  const bf16* wg = Wgu + (size_t)e * (2 * I_) * H_;

  // staging descriptors; XOR swizzle (chunk ^= row&7) applied on the GLOBAL
  // source address so LDS dest stays linear (global_load_lds requirement)
  const bf16* asrc[4]; int aoff[4];
#pragma unroll
  for (int c = 0; c < 4; ++c) {
    int L = c * 256 + t;
    int row = L >> 3, cc = (L & 7) ^ (row & 7);
    int r = m0 + row; if (r >= cnt) r = cnt - 1;
    asrc[c] = Xb + (size_t)tok[base + r] * H_ + cc * 8;
    aoff[c] = L * 16;
  }
  const bf16* gsrc[2]; const bf16* usrc[2]; int boff[2];
#pragma unroll
  for (int c = 0; c < 2; ++c) {
    int L = c * 256 + t;
    int row = L >> 3, cc = (L & 7) ^ (row & 7);
    gsrc[c] = wg + (size_t)(j0 + row) * H_ + cc * 8;
    usrc[c] = wg + (size_t)(I_ + j0 + row) * H_ + cc * 8;
    boff[c] = L * 16;
  }

#define STAGE1(b, k)                                              \
  {                                                               \
    _Pragma("unroll")                                             \
    for (int c = 0; c < 4; ++c)                                   \
      gl2lds16(asrc[c] + (k), (char*)lA[b] + aoff[c]);            \
    _Pragma("unroll")                                             \
    for (int c = 0; c < 2; ++c) {                                 \
      gl2lds16(gsrc[c] + (k), (char*)lBg[b] + boff[c]);           \
      gl2lds16(usrc[c] + (k), (char*)lBu[b] + boff[c]);           \
    }                                                             \
  }

  f32x4 zero = {0.f, 0.f, 0.f, 0.f};
  f32x4 ag[4][2], au[4][2];
#pragma unroll
  for (int m = 0; m < 4; ++m)
#pragma unroll
    for (int n = 0; n < 2; ++n) { ag[m][n] = zero; au[m][n] = zero; }

  const int lo = lane & 15, hi = lane >> 4;

  STAGE1(0, 0);
  __syncthreads();  // drains vmcnt before barrier (compiler-inserted)

  for (int k0 = 0; k0 < H_; k0 += 128) {
#pragma unroll
    for (int p = 0; p < 2; ++p) {
      const int kc = k0 + p * 64;
      if (kc + 64 < H_) STAGE1(p ^ 1, kc + 64);   // prefetch next tile
#pragma unroll
      for (int kk = 0; kk < 2; ++kk) {
        const int chunk = kk * 4 + hi;
        bf16x8 af[4], bg[2], bu[2];
#pragma unroll
        for (int m = 0; m < 4; ++m) {
          int row = wr * 64 + m * 16 + lo;
          af[m] = *(const bf16x8*)((const char*)lA[p] + row * 128 + ((chunk ^ (row & 7)) * 16));
        }
#pragma unroll
        for (int n = 0; n < 2; ++n) {
          int row = wc * 32 + n * 16 + lo;
          int sw = (chunk ^ (row & 7)) * 16;
          bg[n] = *(const bf16x8*)((const char*)lBg[p] + row * 128 + sw);
          bu[n] = *(const bf16x8*)((const char*)lBu[p] + row * 128 + sw);
        }
        __builtin_amdgcn_s_setprio(1);
#pragma unroll
        for (int m = 0; m < 4; ++m)
#pragma unroll
          for (int n = 0; n < 2; ++n) {
            ag[m][n] = __builtin_amdgcn_mfma_f32_16x16x32_bf16(af[m], bg[n], ag[m][n], 0, 0, 0);
            au[m][n] = __builtin_amdgcn_mfma_f32_16x16x32_bf16(af[m], bu[n], au[m][n], 0, 0, 0);
          }
        __builtin_amdgcn_s_setprio(0);
      }
      __syncthreads();  // staged data ready; ds_reads of buf p drained
    }
  }
#undef STAGE1

#pragma unroll
  for (int m = 0; m < 4; ++m)
#pragma unroll
    for (int r = 0; r < 4; ++r) {
      int row = m0 + wr * 64 + m * 16 + hi * 4 + r;
      if (row < cnt) {
        bf16* dst = act + (size_t)(base + row) * I_ + j0 + wc * 32 + lo;
#pragma unroll
        for (int n = 0; n < 2; ++n) {
          float g = ag[m][n][r], u = au[m][n][r];
          dst[n * 16] = (bf16)(g / (1.f + __expf(-g)) * u);
        }
      }
    }
}

// ---------------- GEMM2: out[tok] += w * (act @ Wd^T) ----------------
// tile: 128 rows x 128 cols, BK=64, 4 waves (2x2), 2-ph dbuf, atomic add
__global__ __launch_bounds__(256) void gemm2_k(const bf16* __restrict__ act,
                                               const bf16* __restrict__ Wd,
                                               const int* __restrict__ ctl,
                                               const int* __restrict__ tok,
                                               const float* __restrict__ sw,
                                               float* __restrict__ out) {
  constexpr int NJ = H_ / 128;       // 16
  constexpr int NM = T_ / 128;       // 64
  constexpr int NB = NJ * NM * E_;   // 8192
  const int L0 = ((int)blockIdx.x & 7) * (NB >> 3) + ((int)blockIdx.x >> 3);
  const int e = L0 / (NJ * NM);
  const int rem = L0 - e * (NJ * NM);
  const int m0 = (rem / NJ) * 128;
  const int n0 = (rem % NJ) * 128;
  const int cnt = ctl[e];
  if (m0 >= cnt) return;
  const int base = ctl[8 + e];

  __shared__ bf16 lA[2][128 * 64];
  __shared__ bf16 lB[2][128 * 64];

  const int t = threadIdx.x;
  const int lane = t & 63;
  const int wr = (t >> 7) & 1;
  const int wc = (t >> 6) & 1;
  const bf16* wd = Wd + (size_t)e * H_ * I_;

  const bf16* asrc[4]; int aoff[4];
#pragma unroll
  for (int c = 0; c < 4; ++c) {
    int L = c * 256 + t;
    int row = L >> 3, cc = (L & 7) ^ (row & 7);
    int r = m0 + row; if (r >= cnt) r = cnt - 1;
    asrc[c] = act + (size_t)(base + r) * I_ + cc * 8;
    aoff[c] = L * 16;
  }
  const bf16* bsrc[4]; int boff[4];
#pragma unroll
  for (int c = 0; c < 4; ++c) {
    int L = c * 256 + t;
    int row = L >> 3, cc = (L & 7) ^ (row & 7);
    bsrc[c] = wd + (size_t)(n0 + row) * I_ + cc * 8;
    boff[c] = L * 16;
  }

#define STAGE2(b, k)                                              \
  {                                                               \
    _Pragma("unroll")                                             \
    for (int c = 0; c < 4; ++c)                                   \
      gl2lds16(asrc[c] + (k), (char*)lA[b] + aoff[c]);            \
    _Pragma("unroll")                                             \
    for (int c = 0; c < 4; ++c)                                   \
      gl2lds16(bsrc[c] + (k), (char*)lB[b] + boff[c]);            \
  }

  f32x4 zero = {0.f, 0.f, 0.f, 0.f};
  f32x4 acc[4][4];
#pragma unroll
  for (int m = 0; m < 4; ++m)
#pragma unroll
    for (int n = 0; n < 4; ++n) acc[m][n] = zero;

  const int lo = lane & 15, hi = lane >> 4;

  STAGE2(0, 0);
  __syncthreads();

  for (int k0 = 0; k0 < I_; k0 += 128) {
#pragma unroll
    for (int p = 0; p < 2; ++p) {
      const int kc = k0 + p * 64;
      if (kc + 64 < I_) STAGE2(p ^ 1, kc + 64);
#pragma unroll
      for (int kk = 0; kk < 2; ++kk) {
        const int chunk = kk * 4 + hi;
        bf16x8 af[4], bb[4];
#pragma unroll
        for (int m = 0; m < 4; ++m) {
          int row = wr * 64 + m * 16 + lo;
          af[m] = *(const bf16x8*)((const char*)lA[p] + row * 128 + ((chunk ^ (row & 7)) * 16));
        }
#pragma unroll
        for (int n = 0; n < 4; ++n) {
          int row = wc * 64 + n * 16 + lo;
          bb[n] = *(const bf16x8*)((const char*)lB[p] + row * 128 + ((chunk ^ (row & 7)) * 16));
        }
        __builtin_amdgcn_s_setprio(1);
#pragma unroll
        for (int m = 0; m < 4; ++m)
#pragma unroll
          for (int n = 0; n < 4; ++n)
            acc[m][n] = __builtin_amdgcn_mfma_f32_16x16x32_bf16(af[m], bb[n], acc[m][n], 0, 0, 0);
        __builtin_amdgcn_s_setprio(0);
      }
      __syncthreads();
    }
  }
#undef STAGE2

#pragma unroll
  for (int m = 0; m < 4; ++m)
#pragma unroll
    for (int r = 0; r < 4; ++r) {
      int row = m0 + wr * 64 + m * 16 + hi * 4 + r;
      if (row < cnt) {
        int token = tok[base + row];
        float w = sw[base + row];
        float* dst = out + (size_t)token * H_ + n0 + wc * 64 + lo;
#pragma unroll
        for (int n = 0; n < 4; ++n) atomicAdd(&dst[n * 16], w * acc[m][n][r]);
      }
    }
}

// ---------------- host launch ----------------
extern "C" void kernel_launch(void* const* d_in, const int* in_sizes, int n_in,
                              void* d_out, int out_size, void* d_ws, size_t ws_size,
                              hipStream_t stream) {
  const float* X = (const float*)d_in[0];
  const float* R = (const float*)d_in[1];
  const float* Wgu = (const float*)d_in[2];
  const float* Wd = (const float*)d_in[3];
  float* out = (float*)d_out;

  char* ws = (char*)d_ws;
  size_t o = 0;
  auto alloc = [&](size_t sz) { void* p = ws + o; o += (sz + 255) & ~(size_t)255; return p; };
  bf16* wgu_bf = (bf16*)alloc(sizeof(bf16) * (size_t)E_ * 2 * I_ * H_);
  bf16* wd_bf  = (bf16*)alloc(sizeof(bf16) * (size_t)E_ * H_ * I_);
  bf16* xbf    = (bf16*)alloc(sizeof(bf16) * (size_t)T_ * H_);
  bf16* actb   = (bf16*)alloc(sizeof(bf16) * (size_t)NSLOT * I_);
  int* sel     = (int*)alloc(4 * NSLOT);
  float* wts   = (float*)alloc(4 * NSLOT);
  int* tokb    = (int*)alloc(4 * NSLOT);
  float* swb   = (float*)alloc(4 * NSLOT);
  int* ctl     = (int*)alloc(4 * 32);

  hipMemsetAsync(d_out, 0, sizeof(float) * (size_t)out_size, stream);
  hipMemsetAsync(ctl, 0, 4 * 32, stream);

  cvt_k<<<2048, 256, 0, stream>>>(Wgu, wgu_bf, (int)((size_t)E_ * 2 * I_ * H_ / 8));
  cvt_k<<<2048, 256, 0, stream>>>(Wd, wd_bf, (int)((size_t)E_ * H_ * I_ / 8));
  router_k<<<T_ / 4, 256, 0, stream>>>(X, R, xbf, sel, wts);
  count_k<<<NSLOT / 256, 256, 0, stream>>>(sel, ctl);
  prefix_k<<<1, 64, 0, stream>>>(ctl);
  scatter_k<<<NSLOT / 256, 256, 0, stream>>>(sel, wts, ctl, tokb, swb);
  gemm1_k<<<I_ / 64 * (T_ / 128) * E_, 256, 0, stream>>>(xbf, wgu_bf, ctl, tokb, actb);
  gemm2_k<<<H_ / 128 * (T_ / 128) * E_, 256, 0, stream>>>(actb, wd_bf, ctl, tokb, swb, out);
}